// Round 6
// baseline (339.116 us; speedup 1.0000x reference)
//
#include <hip/hip_runtime.h>
#include <hip/hip_bf16.h>
#include <stdint.h>

typedef short short8 __attribute__((ext_vector_type(8)));
typedef float f32x4 __attribute__((ext_vector_type(4)));
typedef __hip_bfloat16 bf16;

#define NBATCH 8
#define TSEQ   4096
#define CDIM   1024
#define HDIM   128
#define QK_SCALE 0.08838834764831845f   // 1/sqrt(128)
#define LOG2E    1.4426950408889634f

// attn schedule: 16 chunks of 256 q; chunk c has 4(c+1) kv-tiles of 64;
// n(c) = ceil(4(c+1)/10) items -> Sigma = 61 items/batch, 488 blocks.
#define NITEMS_PB 61
static __device__ __host__ __forceinline__ int nsplits(int c) {
  return (4 * (c + 1) + 9) / 10;
}

// ---- helpers -------------------------------------------------------------
static __device__ __forceinline__ uint32_t cvt_pk_bf16(float lo, float hi) {
  uint32_t r;
  asm("v_cvt_pk_bf16_f32 %0, %1, %2" : "=v"(r) : "v"(lo), "v"(hi));
  return r;
}
static __device__ __forceinline__ short8 pack_bf16x8(float4 a, float4 b) {
  union { short8 v; uint32_t u[4]; } r;
  r.u[0] = cvt_pk_bf16(a.x, a.y);
  r.u[1] = cvt_pk_bf16(a.z, a.w);
  r.u[2] = cvt_pk_bf16(b.x, b.y);
  r.u[3] = cvt_pk_bf16(b.z, b.w);
  return r.v;
}
static __device__ __forceinline__ f32x4 mfma16(short8 a, short8 b, f32x4 c) {
  return __builtin_amdgcn_mfma_f32_16x16x32_bf16(a, b, c, 0, 0, 0);
}
// raw barrier: no vmcnt drain (keep prefetch loads in flight)
#define BAR() do {                                          \
    asm volatile("s_waitcnt lgkmcnt(0)" ::: "memory");      \
    __builtin_amdgcn_s_barrier();                           \
    __builtin_amdgcn_sched_barrier(0);                      \
  } while (0)

// ---- prep: W -> bf16 cast + rope cos/sin table ----------------------------
__global__ void prep_kernel(const float* __restrict__ Wq,
                            const float* __restrict__ Wk,
                            const float* __restrict__ Wv,
                            bf16* __restrict__ W3,
                            float2* __restrict__ cs) {
  int idx = blockIdx.x * 256 + threadIdx.x;
  if (idx < 3 * HDIM * CDIM) {
    int which = idx >> 17;
    int off   = idx & 131071;
    const float* s = (which == 0) ? Wq : (which == 1) ? Wk : Wv;
    W3[idx] = __float2bfloat16(s[off]);
  }
  if (idx < TSEQ * 64) {
    int t = idx >> 6, i = idx & 63;
    float freq = powf(10000.0f, -(float)i * (1.0f / 64.0f));
    float ang  = (float)t * freq;
    cs[idx] = make_float2(cosf(ang), sinf(ang));
  }
}

// ---- projection: LDS-staged x (bf16, swizzled, dbuf), depth-2 x prefetch ---
// grid 512, block 512 (8 waves). Block = 64 rows x 384 cols (24 col-frags,
// 3 per wave). 16 K64 steps; x HBM loads issued ~2 steps ahead.
__global__ __launch_bounds__(512, 4) void proj_kernel(
    const float* __restrict__ x, const bf16* __restrict__ W3,
    const float2* __restrict__ cs, bf16* __restrict__ qbuf,
    bf16* __restrict__ kbuf, bf16* __restrict__ vt) {
  __shared__ __align__(16) char xlds[2][8192];
  const int tid = threadIdx.x, lane = tid & 63, wid = tid >> 6;
  const int qt = lane & 15, g = lane >> 4;
  const int row0 = blockIdx.x * 64;
  const int swz = (qt & 7) << 4;

  const int srow = tid >> 3;
  const int sbyte = srow * 128 + (((tid & 7) * 16) ^ ((srow & 7) << 4));
  const float* xsrc = x + (size_t)(row0 + srow) * CDIM + (tid & 7) * 8;

  const int cf0 = wid * 3;   // col-frags cf0..cf0+2 ; cf<16 -> q/k, else v
  const bf16* wr0 = W3 + (size_t)(cf0 * 16 + qt) * CDIM + g * 8;
  const bf16* wr1 = wr0 + (size_t)16 * CDIM;
  const bf16* wr2 = wr0 + (size_t)32 * CDIM;

  f32x4 acc[3][4];
#pragma unroll
  for (int j = 0; j < 3; ++j)
#pragma unroll
    for (int ti = 0; ti < 4; ++ti) acc[j][ti] = (f32x4){0.f, 0.f, 0.f, 0.f};

  // prologue: stage step 0; x regs for steps 1,2; W for i=0,1
  {
    float4 c0 = *(const float4*)(xsrc), c1 = *(const float4*)(xsrc + 4);
    *(short8*)(&xlds[0][sbyte]) = pack_bf16x8(c0, c1);
  }
  float4 xr[2][2];
  xr[1][0] = *(const float4*)(xsrc + 64);
  xr[1][1] = *(const float4*)(xsrc + 68);
  xr[0][0] = *(const float4*)(xsrc + 128);
  xr[0][1] = *(const float4*)(xsrc + 132);
  short8 wbuf[2][3];
#pragma unroll
  for (int ii = 0; ii < 2; ++ii) {
    wbuf[ii][0] = *(const short8*)(wr0 + ii * 32);
    wbuf[ii][1] = *(const short8*)(wr1 + ii * 32);
    wbuf[ii][2] = *(const short8*)(wr2 + ii * 32);
  }
  BAR();

#pragma unroll
  for (int i = 0; i < 32; ++i) {      // i = s*2 + ks, K32-step index
    const int s = i >> 1, ks = i & 1;
    const char* xb = xlds[s & 1];
    short8 xa[4];
#pragma unroll
    for (int ti = 0; ti < 4; ++ti)
      xa[ti] = *(const short8*)(xb + (ti * 16 + qt) * 128 + ((ks * 64 + g * 16) ^ swz));
    const short8 w0 = wbuf[i & 1][0];
    const short8 w1 = wbuf[i & 1][1];
    const short8 w2 = wbuf[i & 1][2];
#pragma unroll
    for (int ti = 0; ti < 4; ++ti) {
      acc[0][ti] = (cf0 + 0 < 16) ? mfma16(xa[ti], w0, acc[0][ti]) : mfma16(w0, xa[ti], acc[0][ti]);
      acc[1][ti] = (cf0 + 1 < 16) ? mfma16(xa[ti], w1, acc[1][ti]) : mfma16(w1, xa[ti], acc[1][ti]);
      acc[2][ti] = (cf0 + 2 < 16) ? mfma16(xa[ti], w2, acc[2][ti]) : mfma16(w2, xa[ti], acc[2][ti]);
    }
    const int ki = i + 2;
    const int ko2 = (ki < 32) ? ki * 32 : 0;
    wbuf[i & 1][0] = *(const short8*)(wr0 + ko2);
    wbuf[i & 1][1] = *(const short8*)(wr1 + ko2);
    wbuf[i & 1][2] = *(const short8*)(wr2 + ko2);
    if (ks == 1) {
      if (s < 15)   // write next tile from regs (consume xr[(s+1)&1])
        *(short8*)(&xlds[(s + 1) & 1][sbyte]) =
            pack_bf16x8(xr[(s + 1) & 1][0], xr[(s + 1) & 1][1]);
      if (s < 13) { // re-fill same slot with step s+3 (issued ~2 steps early)
        xr[(s + 1) & 1][0] = *(const float4*)(xsrc + (s + 3) * 64);
        xr[(s + 1) & 1][1] = *(const float4*)(xsrc + (s + 3) * 64 + 4);
      }
      BAR();
    }
  }

#pragma unroll
  for (int j = 0; j < 3; ++j) {
    const int cf = cf0 + j;
    if (cf < 16) {
      const int n = cf >> 3;
      const int h = (cf & 7) * 16 + qt;
      bf16* dst = n ? kbuf : qbuf;
      const float qmul = n ? 1.0f : (QK_SCALE * LOG2E);
      const float sgn = (h & 1) ? 1.0f : -1.0f;
#pragma unroll
      for (int ti = 0; ti < 4; ++ti)
#pragma unroll
        for (int rr = 0; rr < 4; ++rr) {
          const int grow = row0 + ti * 16 + g * 4 + rr;
          const int trow = grow & (TSEQ - 1);
          const float v = acc[j][ti][rr];
          const float prt = __shfl_xor(v, 1);
          const float2 c_s = cs[trow * 64 + (h >> 1)];
          dst[(size_t)grow * HDIM + h] =
              __float2bfloat16((v * c_s.x + prt * c_s.y * sgn) * qmul);
        }
    } else {
#pragma unroll
      for (int ti = 0; ti < 4; ++ti)
#pragma unroll
        for (int rr = 0; rr < 4; ++rr) {
          const int h = (cf & 7) * 16 + g * 4 + rr;
          const int grow = row0 + ti * 16 + qt;
          vt[(size_t)(grow >> 12) * (HDIM * TSEQ) + (size_t)h * TSEQ + (grow & (TSEQ - 1))] =
              __float2bfloat16(acc[j][ti][rr]);
        }
    }
  }
}

// ---- attention: 8-wave 256-q blocks, KVBLK=64 LDS dbuf, static 1-item/block -
// grid 488 x 512thr. bid: b=bid&7 (XCD pin), j=bid>>3 -> (chunk c, split s)
// heavy-first. Item = 256-q chunk c x kv tiles [tile0, tile0+len) of 64.
// LDS per buf: K [64][256B swizzled] @0 + V^T [128][128B swizzled] @16384.
struct Stage { short8 v[4]; };

static __device__ __forceinline__ void stage_load(Stage& s, const bf16* kbb,
                                                  const bf16* vbb, int kv0,
                                                  int tid) {
#pragma unroll
  for (int i = 0; i < 2; ++i) {   // K: row = tid>>3 (0..63)
    s.v[i] = *(const short8*)(kbb + (size_t)(kv0 + (tid >> 3)) * HDIM +
                              (tid & 7) * 8 + i * 64);
  }
#pragma unroll
  for (int i = 0; i < 2; ++i) {   // V^T: row(d) = tid>>2 (0..127)
    s.v[2 + i] = *(const short8*)(vbb + (size_t)(tid >> 2) * TSEQ + kv0 +
                                  (tid & 3) * 8 + i * 32);
  }
}
static __device__ __forceinline__ void stage_write(const Stage& s, char* buf,
                                                   int tid) {
  {
    const int row = tid >> 3;
#pragma unroll
    for (int i = 0; i < 2; ++i)
      *(short8*)(buf + row * 256 + (((tid & 7) * 16 + i * 128) ^ ((row & 7) << 4))) = s.v[i];
  }
  {
    const int row = tid >> 2;
#pragma unroll
    for (int i = 0; i < 2; ++i)
      *(short8*)(buf + 16384 + row * 128 + (((tid & 3) * 16 + i * 64) ^ ((row & 7) << 4))) = s.v[2 + i];
  }
}

__global__ __launch_bounds__(512, 4) void attn_kernel(
    const bf16* __restrict__ qbuf, const bf16* __restrict__ kbuf,
    const bf16* __restrict__ vt, bf16* __restrict__ part,
    float2* __restrict__ ml) {
  __shared__ __align__(16) char lds[2][32768];
  const int tid = threadIdx.x, lane = tid & 63, wid = tid >> 6;
  const int qt = lane & 15, g = lane >> 4;
  const int bid = blockIdx.x;
  const int b = bid & 7;                 // batch -> XCD pin
  // decode item (bid>>3) -> (c, split), heavy-first (c=15 first)
  int c = 15, jj = bid >> 3, n;
  while (jj >= (n = nsplits(c))) { jj -= n; --c; }
  const int T = 4 * (c + 1);
  const int base = T / n, r = T % n;
  const int tile0 = jj * base + min(jj, r);
  const int len = base + (jj < r ? 1 : 0);
  const int qminw = c * 256 + wid * 32;
  const int swz = (qt & 7) << 4;
  const int L0 = qt | ((g & 1) << 5);
  const int L1 = L0 + 16;
  const int sel = g >> 1;

  const bf16* kbb = kbuf + (size_t)b * TSEQ * HDIM;
  const bf16* vbb = vt + (size_t)b * HDIM * TSEQ;

  short8 qf8[2][4];
#pragma unroll
  for (int qf = 0; qf < 2; ++qf)
#pragma unroll
    for (int ks = 0; ks < 4; ++ks)
      qf8[qf][ks] = *(const short8*)(qbuf +
          (size_t)(b * TSEQ + qminw + qf * 16 + qt) * HDIM + ks * 32 + g * 8);

  f32x4 acc[8][2];
#pragma unroll
  for (int dt = 0; dt < 8; ++dt)
#pragma unroll
    for (int qf = 0; qf < 2; ++qf) acc[dt][qf] = (f32x4){0.f, 0.f, 0.f, 0.f};
  float m[2] = {-3.0e38f, -3.0e38f}, l[2] = {0.f, 0.f};

  Stage st;
  stage_load(st, kbb, vbb, tile0 * 64, tid);
  stage_write(st, lds[0], tid);
  BAR();

  for (int t = 0; t < len; ++t) {
    const int kv0 = (tile0 + t) * 64;
    const bool hn = (t + 1 < len);
    if (hn) stage_load(st, kbb, vbb, kv0 + 64, tid);  // in flight over compute

    const char* Kl = lds[t & 1];
    const char* Vl = Kl + 16384;
#pragma unroll
    for (int half = 0; half < 2; ++half) {
      const int kvh = kv0 + half * 32;
      if (kvh > qminw + 31) continue;    // fully masked 32-kv half (32-aligned: safe)
      // ---- QK^T (swapped: lane owns q = qf*16+qt; kv = kvh+kt*16+g*4+rr)
      f32x4 sc[2][2];
#pragma unroll
      for (int qf = 0; qf < 2; ++qf)
#pragma unroll
        for (int kt = 0; kt < 2; ++kt) sc[qf][kt] = (f32x4){0.f, 0.f, 0.f, 0.f};
      __builtin_amdgcn_s_setprio(1);
#pragma unroll
      for (int kt = 0; kt < 2; ++kt) {
        const int krow = half * 32 + kt * 16 + qt;
        short8 kf[4];
#pragma unroll
        for (int ks = 0; ks < 4; ++ks)
          kf[ks] = *(const short8*)(Kl + krow * 256 + ((ks * 64 + g * 16) ^ swz));
#pragma unroll
        for (int ks = 0; ks < 4; ++ks) {
          sc[0][kt] = mfma16(kf[ks], qf8[0][ks], sc[0][kt]);
          sc[1][kt] = mfma16(kf[ks], qf8[1][ks], sc[1][kt]);
        }
      }
      __builtin_amdgcn_s_setprio(0);
      // ---- causal mask (only the diagonal-straddling half)
      if (kvh + 31 > qminw) {
#pragma unroll
        for (int qf = 0; qf < 2; ++qf) {
          const int q = qminw + qf * 16 + qt;
#pragma unroll
          for (int kt = 0; kt < 2; ++kt)
#pragma unroll
            for (int rr = 0; rr < 4; ++rr)
              if (kvh + kt * 16 + g * 4 + rr > q) sc[qf][kt][rr] = -1.0e30f;
        }
      }
      // ---- online softmax (exp2 domain; scale*log2e folded into q)
      short8 pbv[2];
#pragma unroll
      for (int qf = 0; qf < 2; ++qf) {
        float tmax = fmaxf(fmaxf(fmaxf(sc[qf][0][0], sc[qf][0][1]),
                                 fmaxf(sc[qf][0][2], sc[qf][0][3])),
                           fmaxf(fmaxf(sc[qf][1][0], sc[qf][1][1]),
                                 fmaxf(sc[qf][1][2], sc[qf][1][3])));
        tmax = fmaxf(tmax, __shfl_xor(tmax, 16));
        tmax = fmaxf(tmax, __shfl_xor(tmax, 32));
        if (__any(tmax > m[qf] + 8.0f)) {   // defer-max (T13)
          const float mn = fmaxf(m[qf], tmax);
          const float f = exp2f(m[qf] - mn);
          l[qf] *= f;
#pragma unroll
          for (int dt = 0; dt < 8; ++dt) {
            acc[dt][qf][0] *= f; acc[dt][qf][1] *= f;
            acc[dt][qf][2] *= f; acc[dt][qf][3] *= f;
          }
          m[qf] = mn;
        }
        float psum = 0.f;
#pragma unroll
        for (int kt = 0; kt < 2; ++kt)
#pragma unroll
          for (int rr = 0; rr < 4; ++rr) {
            const float p = exp2f(sc[qf][kt][rr] - m[qf]);
            sc[qf][kt][rr] = p; psum += p;
          }
        l[qf] += psum;
        // pack P -> bf16 B-frag (k = g*8+j within this 32-kv half)
        const uint32_t pk00 = cvt_pk_bf16(sc[qf][0][0], sc[qf][0][1]);
        const uint32_t pk01 = cvt_pk_bf16(sc[qf][0][2], sc[qf][0][3]);
        const uint32_t pk10 = cvt_pk_bf16(sc[qf][1][0], sc[qf][1][1]);
        const uint32_t pk11 = cvt_pk_bf16(sc[qf][1][2], sc[qf][1][3]);
        const int a00 = __shfl((int)pk00, L0), a10 = __shfl((int)pk10, L0);
        const int a01 = __shfl((int)pk01, L0), a11 = __shfl((int)pk11, L0);
        const int a02 = __shfl((int)pk00, L1), a12 = __shfl((int)pk10, L1);
        const int a03 = __shfl((int)pk01, L1), a13 = __shfl((int)pk11, L1);
        union { short8 v; uint32_t u[4]; } pbu;
        pbu.u[0] = (uint32_t)(sel ? a10 : a00);
        pbu.u[1] = (uint32_t)(sel ? a11 : a01);
        pbu.u[2] = (uint32_t)(sel ? a12 : a02);
        pbu.u[3] = (uint32_t)(sel ? a13 : a03);
        pbv[qf] = pbu.v;
      }
      // ---- PV: acc[dt] += V^T-frag x P-frag
      __builtin_amdgcn_s_setprio(1);
#pragma unroll
      for (int dt = 0; dt < 8; ++dt) {
        const short8 vf = *(const short8*)(Vl + (dt * 16 + qt) * 128 +
                                           ((half * 64 + g * 16) ^ swz));
        acc[dt][0] = mfma16(vf, pbv[0], acc[dt][0]);
        acc[dt][1] = mfma16(vf, pbv[1], acc[dt][1]);
      }
      __builtin_amdgcn_s_setprio(0);
    }

    if (hn) stage_write(st, lds[(t + 1) & 1], tid);
    BAR();
  }

  // ---- store own-normalized bf16 partial + (m,l)
#pragma unroll
  for (int qf = 0; qf < 2; ++qf) {
    float ls = l[qf];
    ls += __shfl_xor(ls, 16);
    ls += __shfl_xor(ls, 32);
    const float inv = ls > 0.f ? 1.0f / ls : 0.f;
    const int row = wid * 32 + qf * 16 + qt;      // row within 256-q chunk
    bf16* prow = part + (size_t)bid * 32768 + (size_t)row * 128;
#pragma unroll
    for (int dt = 0; dt < 8; ++dt) {
      *(uint32_t*)(prow + dt * 16 + g * 4) =
          cvt_pk_bf16(acc[dt][qf][0] * inv, acc[dt][qf][1] * inv);
      *(uint32_t*)(prow + dt * 16 + g * 4 + 2) =
          cvt_pk_bf16(acc[dt][qf][2] * inv, acc[dt][qf][3] * inv);
    }
    if (g == 0) ml[(size_t)bid * 256 + row] = make_float2(m[qf], ls);
  }
}

// ---- combine splits -> final f32 output ------------------------------------
// grid 256 (= 8b x 16c x 2 row-halves), 256 thr: row = rh*128 + (t>>1),
// d-half = (t&1)*64. ns(c) <= 7.
__global__ __launch_bounds__(256) void combine_kernel(
    float* __restrict__ outp, const bf16* __restrict__ part,
    const float2* __restrict__ ml) {
  const int blk = blockIdx.x;
  const int b = blk & 7, c = (blk >> 3) & 15, rh = blk >> 7;
  int j0 = 0;
  for (int cc = 15; cc > c; --cc) j0 += nsplits(cc);
  const int ns = nsplits(c);             // 1..7
  const int t = threadIdx.x;
  const int row = rh * 128 + (t >> 1), dh = (t & 1) << 6;

  float w[8];
  float mstar = -3.0e38f;
#pragma unroll
  for (int s = 0; s < 8; ++s) {
    w[s] = 0.f;
    if (s < ns) {
      const float2 v = ml[(size_t)((j0 + s) * 8 + b) * 256 + row];
      mstar = fmaxf(mstar, v.x);
    }
  }
  float wsum = 0.f;
#pragma unroll
  for (int s = 0; s < 8; ++s)
    if (s < ns) {
      const float2 v = ml[(size_t)((j0 + s) * 8 + b) * 256 + row];
      w[s] = exp2f(v.x - mstar) * v.y;
      wsum += w[s];
    }
  const float inv = 1.0f / wsum;
#pragma unroll
  for (int s = 0; s < 8; ++s) w[s] *= inv;

  float* orow = outp + (size_t)(b * TSEQ + c * 256 + row) * HDIM + dh;
#pragma unroll
  for (int jjj = 0; jjj < 64; jjj += 8) {
    float rsum[8] = {0.f, 0.f, 0.f, 0.f, 0.f, 0.f, 0.f, 0.f};
#pragma unroll
    for (int s = 0; s < 8; ++s)
      if (s < ns) {
        const short8 pv = *(const short8*)(part +
            (size_t)((j0 + s) * 8 + b) * 32768 + (size_t)row * 128 + dh + jjj);
#pragma unroll
        for (int e = 0; e < 8; ++e) {
          union { uint32_t u; float f; } cv;
          cv.u = ((uint32_t)(uint16_t)pv[e]) << 16;
          rsum[e] += w[s] * cv.f;
        }
      }
    *(float4*)(orow + jjj) = make_float4(rsum[0], rsum[1], rsum[2], rsum[3]);
    *(float4*)(orow + jjj + 4) = make_float4(rsum[4], rsum[5], rsum[6], rsum[7]);
  }
}

// ---- launch ----------------------------------------------------------------
extern "C" void kernel_launch(void* const* d_in, const int* in_sizes, int n_in,
                              void* d_out, int out_size, void* d_ws, size_t ws_size,
                              hipStream_t stream) {
  (void)in_sizes; (void)n_in; (void)out_size; (void)ws_size;
  const float* x  = (const float*)d_in[0];
  const float* Wq = (const float*)d_in[1];
  const float* Wk = (const float*)d_in[2];
  const float* Wv = (const float*)d_in[3];
  float* out = (float*)d_out;

  // ws (44 MiB used): cs@0 (2M) | W3@2M (1M) | q@3M (8M) | k@11M (8M)
  //   | vt@19M (8M) | ml@27M (1M: 488*256*8B) | part@28M (15.3M: 488*32KB)
  char* ws = (char*)d_ws;
  float2* cs   = (float2*)(ws);
  bf16*   W3   = (bf16*)(ws + (2u  << 20));
  bf16*   qbuf = (bf16*)(ws + (3u  << 20));
  bf16*   kbuf = (bf16*)(ws + (11u << 20));
  bf16*   vt   = (bf16*)(ws + (19u << 20));
  float2* ml   = (float2*)(ws + (27u << 20));
  bf16*   part = (bf16*)(ws + (28u << 20));

  hipLaunchKernelGGL(prep_kernel, dim3(1536), dim3(256), 0, stream, Wq, Wk, Wv, W3, cs);
  hipLaunchKernelGGL(proj_kernel, dim3(512), dim3(512), 0, stream, x, W3, cs, qbuf, kbuf, vt);
  hipLaunchKernelGGL(attn_kernel, dim3(NITEMS_PB * 8), dim3(512), 0, stream,
                     qbuf, kbuf, vt, part, ml);
  hipLaunchKernelGGL(combine_kernel, dim3(256), dim3(256), 0, stream, out, part, ml);
}

// Round 7
// 193.918 us; speedup vs baseline: 1.7488x; 1.7488x over previous
//
#include <hip/hip_runtime.h>
#include <hip/hip_bf16.h>
#include <stdint.h>

typedef short short8 __attribute__((ext_vector_type(8)));
typedef float f32x4 __attribute__((ext_vector_type(4)));
typedef __hip_bfloat16 bf16;

#define NBATCH 8
#define TSEQ   4096
#define CDIM   1024
#define HDIM   128
#define QK_SCALE 0.08838834764831845f   // 1/sqrt(128)
#define LOG2E    1.4426950408889634f

// attn schedule: 32 chunks of 128 q per batch; chunk c has T=2(c+1) kv-tiles
// of 64; n(c) = ceil((c+1)/11) splits (max window 22 tiles).
// Sum_c n(c) = 63 items/batch -> 504 blocks (<= 512 resident slots, ONE
// generation at 2 blocks/CU). NOTE: __launch_bounds__ 2nd arg acts as min
// BLOCKS/CU on this toolchain (R6: (512,4) forced VGPR=64 -> spill storm).
// Do not use it.
#define NITEMS_PB 63
static __device__ __host__ __forceinline__ int nsplits(int c) {
  return (c + 11) / 11;
}

// ---- helpers -------------------------------------------------------------
static __device__ __forceinline__ uint32_t cvt_pk_bf16(float lo, float hi) {
  uint32_t r;
  asm("v_cvt_pk_bf16_f32 %0, %1, %2" : "=v"(r) : "v"(lo), "v"(hi));
  return r;
}
static __device__ __forceinline__ short8 pack_bf16x8(float4 a, float4 b) {
  union { short8 v; uint32_t u[4]; } r;
  r.u[0] = cvt_pk_bf16(a.x, a.y);
  r.u[1] = cvt_pk_bf16(a.z, a.w);
  r.u[2] = cvt_pk_bf16(b.x, b.y);
  r.u[3] = cvt_pk_bf16(b.z, b.w);
  return r.v;
}
static __device__ __forceinline__ f32x4 mfma16(short8 a, short8 b, f32x4 c) {
  return __builtin_amdgcn_mfma_f32_16x16x32_bf16(a, b, c, 0, 0, 0);
}
// raw barrier: no vmcnt drain (keep prefetch loads in flight)
#define BAR() do {                                          \
    asm volatile("s_waitcnt lgkmcnt(0)" ::: "memory");      \
    __builtin_amdgcn_s_barrier();                           \
    __builtin_amdgcn_sched_barrier(0);                      \
  } while (0)

// ---- prep: W -> bf16 cast + rope cos/sin table ----------------------------
__global__ void prep_kernel(const float* __restrict__ Wq,
                            const float* __restrict__ Wk,
                            const float* __restrict__ Wv,
                            bf16* __restrict__ W3,
                            float2* __restrict__ cs) {
  int idx = blockIdx.x * 256 + threadIdx.x;
  if (idx < 3 * HDIM * CDIM) {
    int which = idx >> 17;
    int off   = idx & 131071;
    const float* s = (which == 0) ? Wq : (which == 1) ? Wk : Wv;
    W3[idx] = __float2bfloat16(s[off]);
  }
  if (idx < TSEQ * 64) {
    int t = idx >> 6, i = idx & 63;
    float freq = powf(10000.0f, -(float)i * (1.0f / 64.0f));
    float ang  = (float)t * freq;
    cs[idx] = make_float2(cosf(ang), sinf(ang));
  }
}

// ---- projection: LDS-staged x (bf16, swizzled, dbuf), depth-2 x prefetch ---
// grid 512, block 512 (8 waves). Block = 64 rows x 384 cols.
__global__ __launch_bounds__(512) void proj_kernel(
    const float* __restrict__ x, const bf16* __restrict__ W3,
    const float2* __restrict__ cs, bf16* __restrict__ qbuf,
    bf16* __restrict__ kbuf, bf16* __restrict__ vt) {
  __shared__ __align__(16) char xlds[2][8192];
  const int tid = threadIdx.x, lane = tid & 63, wid = tid >> 6;
  const int qt = lane & 15, g = lane >> 4;
  const int row0 = blockIdx.x * 64;
  const int swz = (qt & 7) << 4;

  const int srow = tid >> 3;
  const int sbyte = srow * 128 + (((tid & 7) * 16) ^ ((srow & 7) << 4));
  const float* xsrc = x + (size_t)(row0 + srow) * CDIM + (tid & 7) * 8;

  const int cf0 = wid * 3;   // col-frags cf0..cf0+2 ; cf<16 -> q/k, else v
  const bf16* wr0 = W3 + (size_t)(cf0 * 16 + qt) * CDIM + g * 8;
  const bf16* wr1 = wr0 + (size_t)16 * CDIM;
  const bf16* wr2 = wr0 + (size_t)32 * CDIM;

  f32x4 acc[3][4];
#pragma unroll
  for (int j = 0; j < 3; ++j)
#pragma unroll
    for (int ti = 0; ti < 4; ++ti) acc[j][ti] = (f32x4){0.f, 0.f, 0.f, 0.f};

  // prologue: stage step 0; x regs for steps 1,2; W for i=0,1
  {
    float4 c0 = *(const float4*)(xsrc), c1 = *(const float4*)(xsrc + 4);
    *(short8*)(&xlds[0][sbyte]) = pack_bf16x8(c0, c1);
  }
  float4 xr[2][2];
  xr[1][0] = *(const float4*)(xsrc + 64);
  xr[1][1] = *(const float4*)(xsrc + 68);
  xr[0][0] = *(const float4*)(xsrc + 128);
  xr[0][1] = *(const float4*)(xsrc + 132);
  short8 wbuf[2][3];
#pragma unroll
  for (int ii = 0; ii < 2; ++ii) {
    wbuf[ii][0] = *(const short8*)(wr0 + ii * 32);
    wbuf[ii][1] = *(const short8*)(wr1 + ii * 32);
    wbuf[ii][2] = *(const short8*)(wr2 + ii * 32);
  }
  BAR();

#pragma unroll
  for (int i = 0; i < 32; ++i) {      // i = s*2 + ks, K32-step index
    const int s = i >> 1, ks = i & 1;
    const char* xb = xlds[s & 1];
    short8 xa[4];
#pragma unroll
    for (int ti = 0; ti < 4; ++ti)
      xa[ti] = *(const short8*)(xb + (ti * 16 + qt) * 128 + ((ks * 64 + g * 16) ^ swz));
    const short8 w0 = wbuf[i & 1][0];
    const short8 w1 = wbuf[i & 1][1];
    const short8 w2 = wbuf[i & 1][2];
#pragma unroll
    for (int ti = 0; ti < 4; ++ti) {
      acc[0][ti] = (cf0 + 0 < 16) ? mfma16(xa[ti], w0, acc[0][ti]) : mfma16(w0, xa[ti], acc[0][ti]);
      acc[1][ti] = (cf0 + 1 < 16) ? mfma16(xa[ti], w1, acc[1][ti]) : mfma16(w1, xa[ti], acc[1][ti]);
      acc[2][ti] = (cf0 + 2 < 16) ? mfma16(xa[ti], w2, acc[2][ti]) : mfma16(w2, xa[ti], acc[2][ti]);
    }
    const int ki = i + 2;
    const int ko2 = (ki < 32) ? ki * 32 : 0;
    wbuf[i & 1][0] = *(const short8*)(wr0 + ko2);
    wbuf[i & 1][1] = *(const short8*)(wr1 + ko2);
    wbuf[i & 1][2] = *(const short8*)(wr2 + ko2);
    if (ks == 1) {
      if (s < 15)   // write next tile from regs
        *(short8*)(&xlds[(s + 1) & 1][sbyte]) =
            pack_bf16x8(xr[(s + 1) & 1][0], xr[(s + 1) & 1][1]);
      if (s < 13) { // re-fill same slot with step s+3 (~2 steps of cover)
        xr[(s + 1) & 1][0] = *(const float4*)(xsrc + (s + 3) * 64);
        xr[(s + 1) & 1][1] = *(const float4*)(xsrc + (s + 3) * 64 + 4);
      }
      BAR();
    }
  }

#pragma unroll
  for (int j = 0; j < 3; ++j) {
    const int cf = cf0 + j;
    if (cf < 16) {
      const int n = cf >> 3;
      const int h = (cf & 7) * 16 + qt;
      bf16* dst = n ? kbuf : qbuf;
      const float qmul = n ? 1.0f : (QK_SCALE * LOG2E);
      const float sgn = (h & 1) ? 1.0f : -1.0f;
#pragma unroll
      for (int ti = 0; ti < 4; ++ti)
#pragma unroll
        for (int rr = 0; rr < 4; ++rr) {
          const int grow = row0 + ti * 16 + g * 4 + rr;
          const int trow = grow & (TSEQ - 1);
          const float v = acc[j][ti][rr];
          const float prt = __shfl_xor(v, 1);
          const float2 c_s = cs[trow * 64 + (h >> 1)];
          dst[(size_t)grow * HDIM + h] =
              __float2bfloat16((v * c_s.x + prt * c_s.y * sgn) * qmul);
        }
    } else {
#pragma unroll
      for (int ti = 0; ti < 4; ++ti)
#pragma unroll
        for (int rr = 0; rr < 4; ++rr) {
          const int h = (cf & 7) * 16 + g * 4 + rr;
          const int grow = row0 + ti * 16 + qt;
          vt[(size_t)(grow >> 12) * (HDIM * TSEQ) + (size_t)h * TSEQ + (grow & (TSEQ - 1))] =
              __float2bfloat16(acc[j][ti][rr]);
        }
    }
  }
}

// ---- attention: R3 geometry + balanced 1-generation split-kv schedule ------
// grid 504 x 256thr (4 waves). bid: b=bid&7 (XCD pin), j=bid>>3 -> (c, split)
// heavy-first. Item = 128-q chunk c x kv-tile window [tile0, tile0+len) of 64.
// LDS/buf (32KB): K [64 rows][256B swz] @0 + V^T [128 rows][128B swz] @16384.
struct Stage { short8 v[8]; };

static __device__ __forceinline__ void stage_load(Stage& s, const bf16* kbb,
                                                  const bf16* vbb, int kv0,
                                                  int wid, int lane) {
  const int g = lane >> 4, qt = lane & 15;
#pragma unroll
  for (int i = 0; i < 4; ++i) {
    const int row = wid * 16 + i * 4 + g;
    s.v[i] = *(const short8*)(kbb + (size_t)(kv0 + row) * HDIM + qt * 8);
  }
#pragma unroll
  for (int i = 0; i < 4; ++i) {
    const int row = wid * 32 + i * 8 + (lane >> 3);
    s.v[4 + i] = *(const short8*)(vbb + (size_t)row * TSEQ + kv0 + (lane & 7) * 8);
  }
}
static __device__ __forceinline__ void stage_write(const Stage& s, char* buf,
                                                   int wid, int lane) {
  const int qt = lane & 15;
  const int g = lane >> 4;
#pragma unroll
  for (int i = 0; i < 4; ++i) {
    const int row = wid * 16 + i * 4 + g;
    *(short8*)(buf + row * 256 + ((qt * 16) ^ ((row & 7) << 4))) = s.v[i];
  }
#pragma unroll
  for (int i = 0; i < 4; ++i) {
    const int row = wid * 32 + i * 8 + (lane >> 3);
    *(short8*)(buf + 16384 + row * 128 + (((lane & 7) * 16) ^ ((row & 7) << 4))) = s.v[4 + i];
  }
}

__global__ __launch_bounds__(256) void attn_kernel(
    const bf16* __restrict__ qbuf, const bf16* __restrict__ kbuf,
    const bf16* __restrict__ vt, bf16* __restrict__ part,
    float2* __restrict__ ml) {
  __shared__ __align__(16) char lds[2][32768];
  const int tid = threadIdx.x, lane = tid & 63, wid = tid >> 6;
  const int qt = lane & 15, g = lane >> 4;
  const int bid = blockIdx.x;
  const int b = bid & 7;                 // batch -> XCD pin
  // decode item (bid>>3) -> (chunk c, split jj), heavy-first (c=31 first)
  int c = 31, jj = bid >> 3, n;
  while (jj >= (n = nsplits(c))) { jj -= n; --c; }
  const int T = 2 * (c + 1);             // 64-kv tiles in chunk
  const int base = T / n, r = T % n;
  const int tile0 = jj * base + min(jj, r);
  const int len = base + (jj < r ? 1 : 0);
  const int qminw = c * 128 + wid * 32;
  const int swz = (qt & 7) << 4;
  const int L0 = qt | ((g & 1) << 5);
  const int L1 = L0 + 16;
  const int sel = g >> 1;

  const bf16* kbb = kbuf + (size_t)b * TSEQ * HDIM;
  const bf16* vbb = vt + (size_t)b * HDIM * TSEQ;

  short8 qf8[2][4];
#pragma unroll
  for (int qf = 0; qf < 2; ++qf)
#pragma unroll
    for (int ks = 0; ks < 4; ++ks)
      qf8[qf][ks] = *(const short8*)(qbuf +
          (size_t)(b * TSEQ + qminw + qf * 16 + qt) * HDIM + ks * 32 + g * 8);

  f32x4 acc[8][2];
#pragma unroll
  for (int dt = 0; dt < 8; ++dt)
#pragma unroll
    for (int qf = 0; qf < 2; ++qf) acc[dt][qf] = (f32x4){0.f, 0.f, 0.f, 0.f};
  float m[2] = {-3.0e38f, -3.0e38f}, l[2] = {0.f, 0.f};

  Stage st;
  stage_load(st, kbb, vbb, tile0 * 64, wid, lane);
  stage_write(st, lds[0], wid, lane);
  BAR();

  for (int t = 0; t < len; ++t) {
    const int kv0 = (tile0 + t) * 64;
    const bool hn = (t + 1 < len);
    if (hn) stage_load(st, kbb, vbb, kv0 + 64, wid, lane);  // in flight over compute

    if (kv0 <= qminw + 31) {             // skip fully-masked tiles (wave level)
      const char* Kl = lds[t & 1];
      const char* Vl = Kl + 16384;
      // ---- QK^T (swapped: lane owns q = qf*16+qt; kv = kv0+kt*16+g*4+rr)
      f32x4 sc[2][4];
#pragma unroll
      for (int qf = 0; qf < 2; ++qf)
#pragma unroll
        for (int kt = 0; kt < 4; ++kt) sc[qf][kt] = (f32x4){0.f, 0.f, 0.f, 0.f};
      __builtin_amdgcn_s_setprio(1);
#pragma unroll
      for (int kt = 0; kt < 4; ++kt) {
        short8 kf[4];
#pragma unroll
        for (int ks = 0; ks < 4; ++ks)
          kf[ks] = *(const short8*)(Kl + (kt * 16 + qt) * 256 + ((ks * 64 + g * 16) ^ swz));
#pragma unroll
        for (int ks = 0; ks < 4; ++ks) {
          sc[0][kt] = mfma16(kf[ks], qf8[0][ks], sc[0][kt]);
          sc[1][kt] = mfma16(kf[ks], qf8[1][ks], sc[1][kt]);
        }
      }
      __builtin_amdgcn_s_setprio(0);
      // ---- causal mask (diagonal-straddling tiles only)
      if (kv0 + 63 > qminw) {
#pragma unroll
        for (int qf = 0; qf < 2; ++qf) {
          const int q = qminw + qf * 16 + qt;
#pragma unroll
          for (int kt = 0; kt < 4; ++kt)
#pragma unroll
            for (int rr = 0; rr < 4; ++rr)
              if (kv0 + kt * 16 + g * 4 + rr > q) sc[qf][kt][rr] = -1.0e30f;
        }
      }
      // ---- online softmax over 64 kv (exp2 domain)
      short8 pbv[2][2];
#pragma unroll
      for (int qf = 0; qf < 2; ++qf) {
        float tmax = -3.0e38f;
#pragma unroll
        for (int kt = 0; kt < 4; ++kt)
#pragma unroll
          for (int rr = 0; rr < 4; ++rr) tmax = fmaxf(tmax, sc[qf][kt][rr]);
        tmax = fmaxf(tmax, __shfl_xor(tmax, 16));
        tmax = fmaxf(tmax, __shfl_xor(tmax, 32));
        if (__any(tmax > m[qf] + 8.0f)) {   // defer-max (T13)
          const float mn = fmaxf(m[qf], tmax);
          const float f = exp2f(m[qf] - mn);
          l[qf] *= f;
#pragma unroll
          for (int dt = 0; dt < 8; ++dt) {
            acc[dt][qf][0] *= f; acc[dt][qf][1] *= f;
            acc[dt][qf][2] *= f; acc[dt][qf][3] *= f;
          }
          m[qf] = mn;
        }
        float psum = 0.f;
#pragma unroll
        for (int kt = 0; kt < 4; ++kt)
#pragma unroll
          for (int rr = 0; rr < 4; ++rr) {
            const float p = exp2f(sc[qf][kt][rr] - m[qf]);
            sc[qf][kt][rr] = p; psum += p;
          }
        l[qf] += psum;
        // pack P -> bf16 B-frags (k = g*8+j), two 32-kv chunks
#pragma unroll
        for (int kch = 0; kch < 2; ++kch) {
          const f32x4 p0 = sc[qf][kch * 2], p1 = sc[qf][kch * 2 + 1];
          const uint32_t pk00 = cvt_pk_bf16(p0[0], p0[1]);
          const uint32_t pk01 = cvt_pk_bf16(p0[2], p0[3]);
          const uint32_t pk10 = cvt_pk_bf16(p1[0], p1[1]);
          const uint32_t pk11 = cvt_pk_bf16(p1[2], p1[3]);
          const int a00 = __shfl((int)pk00, L0), a10 = __shfl((int)pk10, L0);
          const int a01 = __shfl((int)pk01, L0), a11 = __shfl((int)pk11, L0);
          const int a02 = __shfl((int)pk00, L1), a12 = __shfl((int)pk10, L1);
          const int a03 = __shfl((int)pk01, L1), a13 = __shfl((int)pk11, L1);
          union { short8 v; uint32_t u[4]; } pbu;
          pbu.u[0] = (uint32_t)(sel ? a10 : a00);
          pbu.u[1] = (uint32_t)(sel ? a11 : a01);
          pbu.u[2] = (uint32_t)(sel ? a12 : a02);
          pbu.u[3] = (uint32_t)(sel ? a13 : a03);
          pbv[qf][kch] = pbu.v;
        }
      }
      // ---- PV: acc[dt] += V^T-frag x P-frag
      __builtin_amdgcn_s_setprio(1);
#pragma unroll
      for (int dt = 0; dt < 8; ++dt) {
        const short8 vf0 = *(const short8*)(Vl + (dt * 16 + qt) * 128 + ((g * 16) ^ swz));
        const short8 vf1 = *(const short8*)(Vl + (dt * 16 + qt) * 128 + ((64 + g * 16) ^ swz));
        acc[dt][0] = mfma16(vf0, pbv[0][0], acc[dt][0]);
        acc[dt][1] = mfma16(vf0, pbv[1][0], acc[dt][1]);
        acc[dt][0] = mfma16(vf1, pbv[0][1], acc[dt][0]);
        acc[dt][1] = mfma16(vf1, pbv[1][1], acc[dt][1]);
      }
      __builtin_amdgcn_s_setprio(0);
    }

    if (hn) stage_write(st, lds[(t + 1) & 1], wid, lane);
    BAR();
  }

  // ---- store own-normalized bf16 partial + (m,l)
#pragma unroll
  for (int qf = 0; qf < 2; ++qf) {
    float ls = l[qf];
    ls += __shfl_xor(ls, 16);
    ls += __shfl_xor(ls, 32);
    const float inv = ls > 0.f ? 1.0f / ls : 0.f;
    const int row = wid * 32 + qf * 16 + qt;      // row within 128-q chunk
    bf16* prow = part + (size_t)bid * 16384 + (size_t)row * 128;
#pragma unroll
    for (int dt = 0; dt < 8; ++dt) {
      *(uint32_t*)(prow + dt * 16 + g * 4) =
          cvt_pk_bf16(acc[dt][qf][0] * inv, acc[dt][qf][1] * inv);
      *(uint32_t*)(prow + dt * 16 + g * 4 + 2) =
          cvt_pk_bf16(acc[dt][qf][2] * inv, acc[dt][qf][3] * inv);
    }
    if (g == 0) ml[(size_t)bid * 128 + row] = make_float2(m[qf], ls);
  }
}

// ---- combine splits -> final f32 output ------------------------------------
// grid 256 (= 8 b x 32 c), 256 thr: row = t>>1 (0..127), d-half = (t&1)*64.
__global__ __launch_bounds__(256) void combine_kernel(
    float* __restrict__ outp, const bf16* __restrict__ part,
    const float2* __restrict__ ml) {
  const int blk = blockIdx.x;
  const int b = blk & 7, c = blk >> 3;
  int j0 = 0;
  for (int cc = 31; cc > c; --cc) j0 += nsplits(cc);
  const int ns = nsplits(c);             // 1..3
  const int t = threadIdx.x;
  const int row = t >> 1, dh = (t & 1) << 6;

  float w[3] = {0.f, 0.f, 0.f};
  float mstar = -3.0e38f;
#pragma unroll
  for (int s = 0; s < 3; ++s)
    if (s < ns) {
      const float2 v = ml[(size_t)((j0 + s) * 8 + b) * 128 + row];
      mstar = fmaxf(mstar, v.x);
    }
  float wsum = 0.f;
#pragma unroll
  for (int s = 0; s < 3; ++s)
    if (s < ns) {
      const float2 v = ml[(size_t)((j0 + s) * 8 + b) * 128 + row];
      w[s] = exp2f(v.x - mstar) * v.y;
      wsum += w[s];
    }
  const float inv = wsum > 0.f ? 1.0f / wsum : 0.f;
#pragma unroll
  for (int s = 0; s < 3; ++s) w[s] *= inv;

  float* orow = outp + (size_t)(b * TSEQ + c * 128 + row) * HDIM + dh;
#pragma unroll
  for (int jjj = 0; jjj < 64; jjj += 8) {
    float rsum[8] = {0.f, 0.f, 0.f, 0.f, 0.f, 0.f, 0.f, 0.f};
#pragma unroll
    for (int s = 0; s < 3; ++s)
      if (s < ns) {
        const short8 pv = *(const short8*)(part +
            (size_t)((j0 + s) * 8 + b) * 16384 + (size_t)row * 128 + dh + jjj);
#pragma unroll
        for (int e = 0; e < 8; ++e) {
          union { uint32_t u; float f; } cv;
          cv.u = ((uint32_t)(uint16_t)pv[e]) << 16;
          rsum[e] += w[s] * cv.f;
        }
      }
    *(float4*)(orow + jjj) = make_float4(rsum[0], rsum[1], rsum[2], rsum[3]);
    *(float4*)(orow + jjj + 4) = make_float4(rsum[4], rsum[5], rsum[6], rsum[7]);
  }
}

// ---- launch ----------------------------------------------------------------
extern "C" void kernel_launch(void* const* d_in, const int* in_sizes, int n_in,
                              void* d_out, int out_size, void* d_ws, size_t ws_size,
                              hipStream_t stream) {
  (void)in_sizes; (void)n_in; (void)out_size; (void)ws_size;
  const float* x  = (const float*)d_in[0];
  const float* Wq = (const float*)d_in[1];
  const float* Wk = (const float*)d_in[2];
  const float* Wv = (const float*)d_in[3];
  float* out = (float*)d_out;

  // ws (~45 MiB): cs@0 (2M) | W3@2M (1M) | q@3M (8M) | k@11M (8M)
  //   | vt@19M (8M) | ml@27M (0.5M: 504*128*8B) | part@28M (16.5M: 504*32KB)
  char* ws = (char*)d_ws;
  float2* cs   = (float2*)(ws);
  bf16*   W3   = (bf16*)(ws + (2u  << 20));
  bf16*   qbuf = (bf16*)(ws + (3u  << 20));
  bf16*   kbuf = (bf16*)(ws + (11u << 20));
  bf16*   vt   = (bf16*)(ws + (19u << 20));
  float2* ml   = (float2*)(ws + (27u << 20));
  bf16*   part = (bf16*)(ws + (28u << 20));

  hipLaunchKernelGGL(prep_kernel, dim3(1536), dim3(256), 0, stream, Wq, Wk, Wv, W3, cs);
  hipLaunchKernelGGL(proj_kernel, dim3(512), dim3(512), 0, stream, x, W3, cs, qbuf, kbuf, vt);
  hipLaunchKernelGGL(attn_kernel, dim3(NITEMS_PB * 8), dim3(256), 0, stream,
                     qbuf, kbuf, vt, part, ml);
  hipLaunchKernelGGL(combine_kernel, dim3(256), dim3(256), 0, stream, out, part, ml);
}